// Round 5
// baseline (1413.292 us; speedup 1.0000x reference)
//
#include <hip/hip_runtime.h>
#include <math.h>

// Sinkhorn regularized transport, B=8, m=n=1024, fp32, 100 iterations.
//
// Round 5: flag-embedded data. R4 (5.3us/iter) still serialized ~5 L3 round
// trips per iteration: store-drain -> stampA -> owner poll -> 4KB read ->
// v-drain -> stampV -> consumer poll -> 4KB read, plus s_sleep quantization.
// Here every exchanged float carries its iteration stamp in one 8B packet
// {f32 val | u32 iter}:
//  - producers store packed partials immediately after computing them (no
//    drain barrier, no separate stamp publish);
//  - owner block g polls its 32-producer x 32-col packet slice directly and
//    consumes packets as they arrive;
//  - owner publishes packed v-slice; consumers poll packed v directly.
// 8B atomic store/load (agent scope, sc0 sc1 -> L3 coherence point; mechanism
// validated R3/R4) makes each {val,stamp} pair tear-free.
// Single-buffered, monotonic stamps: v[t+1] is published only after all
// partials[t+1] arrived, which requires every block to have consumed all of
// v[t]; partials[t+1] overwrite is gated the same way. Initial contents
// (harness 0xAA poison / memset 0) never match a stamp in [1,101].

#define B_    8
#define N_    1024
#define G_    32          // blocks per batch
#define RPB   32          // rows per block
#define KSTR  1028        // LDS row stride (floats): 16B aligned, bank skew
#define NITER 100
#define TPB   256
#define LMB   10.0f
#define MAXD  5.0f

// LDS: Kl (RPB*KSTR) + vl (N_) + ul (RPB) + red (G_ float4)
#define LDS_FLOATS (RPB * KSTR + N_ + RPB + 4 * G_)

typedef unsigned long long u64;
typedef unsigned int u32;

__device__ __forceinline__ u64 pack(float v, u32 s) {
    return (u64)__float_as_uint(v) | ((u64)s << 32);
}
__device__ __forceinline__ float pval(u64 w) {
    return __uint_as_float((u32)w);
}
__device__ __forceinline__ u32 pst(u64 w) { return (u32)(w >> 32); }

__device__ __forceinline__ void ast(u64* p, u64 v) {
    __hip_atomic_store(p, v, __ATOMIC_RELAXED, __HIP_MEMORY_SCOPE_AGENT);
}
__device__ __forceinline__ u64 ald(const u64* p) {
    return __hip_atomic_load(p, __ATOMIC_RELAXED, __HIP_MEMORY_SCOPE_AGENT);
}

__global__ void __launch_bounds__(TPB, 1)
sinkhorn_kernel(const float* __restrict__ Mg,
                float* __restrict__ Pg,
                u64* __restrict__ ppk,    // [B_][G_][N_] packed partials
                u64* __restrict__ vpk)    // [B_][N_]     packed v
{
    extern __shared__ float lds[];
    float* Kl   = lds;                        // RPB x KSTR
    float* vl   = lds + RPB * KSTR;           // N_
    float* ul   = vl + N_;                    // RPB
    float4* red = (float4*)(ul + RPB);        // G_ float4

    const int b    = blockIdx.x & (B_ - 1);
    const int g    = blockIdx.x >> 3;
    const int t    = threadIdx.x;
    const int row0 = g * RPB;
    const float r = 1.0f / (float)N_;
    const float c = 1.0f / (float)N_;

    // ---- stage K rows into LDS ----
    const float* Mb = Mg + ((size_t)b * N_ + row0) * N_;
    for (int i = 0; i < RPB; ++i) {
        float4 m4 = ((const float4*)(Mb + (size_t)i * N_))[t];
        float4 k4;
        k4.x = expf(-LMB * fminf(m4.x, MAXD));
        k4.y = expf(-LMB * fminf(m4.y, MAXD));
        k4.z = expf(-LMB * fminf(m4.z, MAXD));
        k4.w = expf(-LMB * fminf(m4.w, MAXD));
        *(float4*)&Kl[i * KSTR + 4 * t] = k4;
    }
    if (t < RPB) ul[t] = r;             // u = r initially
    __syncthreads();

    u64* ppk_b = ppk + (size_t)b * G_ * N_;
    u64* vpk_b = vpk + (size_t)b * N_;

    for (int it = 0; it <= NITER; ++it) {
        const u32 st = (u32)(it + 1);

        // ---- phase A: partial[j] = sum_{own rows i} K[i][j] * u_i ----
        float4 a = make_float4(0.f, 0.f, 0.f, 0.f);
#pragma unroll
        for (int i = 0; i < RPB; ++i) {
            const float u  = ul[i];
            const float4 k4 = *(const float4*)&Kl[i * KSTR + 4 * t];
            a.x = fmaf(k4.x, u, a.x);
            a.y = fmaf(k4.y, u, a.y);
            a.z = fmaf(k4.z, u, a.z);
            a.w = fmaf(k4.w, u, a.w);
        }
        {   // packed store: data carries its own validity stamp
            u64* slot = ppk_b + (size_t)g * N_ + 4 * t;
            ast(slot + 0, pack(a.x, st));
            ast(slot + 1, pack(a.y, st));
            ast(slot + 2, pack(a.z, st));
            ast(slot + 3, pack(a.w, st));
        }

        // ---- owner poll+reduce: block g owns cols [32g, 32g+32) ----
        {
            const int gp = t >> 3;           // producer 0..31
            const int q  = t & 7;            // col-quad within our slice
            const u64* src = ppk_b + (size_t)gp * N_ + 32 * g + 4 * q;
            u64 w0, w1, w2, w3;
            for (;;) {
                w0 = ald(src + 0); w1 = ald(src + 1);
                w2 = ald(src + 2); w3 = ald(src + 3);
                if ((pst(w0) == st) & (pst(w1) == st) &
                    (pst(w2) == st) & (pst(w3) == st)) break;
                __builtin_amdgcn_s_sleep(1);
            }
            float4 acc = make_float4(pval(w0), pval(w1), pval(w2), pval(w3));
            // reduce across this wave's 8 producers (lane bits 3..5)
#pragma unroll
            for (int d = 8; d <= 32; d <<= 1) {
                acc.x += __shfl_xor(acc.x, d);
                acc.y += __shfl_xor(acc.y, d);
                acc.z += __shfl_xor(acc.z, d);
                acc.w += __shfl_xor(acc.w, d);
            }
            if ((t & 63) < 8) red[(t >> 6) * 8 + (t & 63)] = acc;
        }
        __syncthreads();
        if (t < 8) {                         // finish reduce, publish packed v
            float4 y4;
            y4.x = red[t].x + red[8 + t].x + red[16 + t].x + red[24 + t].x;
            y4.y = red[t].y + red[8 + t].y + red[16 + t].y + red[24 + t].y;
            y4.z = red[t].z + red[8 + t].z + red[16 + t].z + red[24 + t].z;
            y4.w = red[t].w + red[8 + t].w + red[16 + t].w + red[24 + t].w;
            u64* vdst = vpk_b + 32 * g + 4 * t;
            ast(vdst + 0, pack(c / y4.x, st));
            ast(vdst + 1, pack(c / y4.y, st));
            ast(vdst + 2, pack(c / y4.z, st));
            ast(vdst + 3, pack(c / y4.w, st));
        }

        // ---- consumer: poll full packed v, unpack into LDS ----
        {
            const u64* vsrc = vpk_b + 4 * t;
            u64 w0, w1, w2, w3;
            for (;;) {
                w0 = ald(vsrc + 0); w1 = ald(vsrc + 1);
                w2 = ald(vsrc + 2); w3 = ald(vsrc + 3);
                if ((pst(w0) == st) & (pst(w1) == st) &
                    (pst(w2) == st) & (pst(w3) == st)) break;
                __builtin_amdgcn_s_sleep(1);
            }
            *(float4*)&vl[4 * t] =
                make_float4(pval(w0), pval(w1), pval(w2), pval(w3));
        }
        __syncthreads();

        if (it == NITER) break;              // vl holds final v

        // ---- phase B: z_i = sum_j K[i][j] v_j ; u_i = r / z_i ----
        const int rI = t >> 3;               // 0..31 (row within block)
        const int l  = t & 7;                // 0..7  (8 lanes per row)
        float4 za = make_float4(0.f, 0.f, 0.f, 0.f);
#pragma unroll
        for (int k2 = 0; k2 < 32; ++k2) {
            const int j0 = 4 * l + 32 * k2;
            const float4 k4 = *(const float4*)&Kl[rI * KSTR + j0];
            const float4 vv = *(const float4*)&vl[j0];
            za.x = fmaf(k4.x, vv.x, za.x);
            za.y = fmaf(k4.y, vv.y, za.y);
            za.z = fmaf(k4.z, vv.z, za.z);
            za.w = fmaf(k4.w, vv.w, za.w);
        }
        float z = za.x + za.y + za.z + za.w;
        z += __shfl_xor(z, 1);
        z += __shfl_xor(z, 2);
        z += __shfl_xor(z, 4);
        if (l == 0) ul[rI] = r / z;
        __syncthreads();
    }

    // ---- epilogue: P[i][j] = u_i * K[i][j] * v_j ----
    float* Pb = Pg + ((size_t)b * N_ + row0) * N_;
    const float4 v4 = *(const float4*)&vl[4 * t];
    for (int i = 0; i < RPB; ++i) {
        const float u  = ul[i];
        const float4 k4 = *(const float4*)&Kl[i * KSTR + 4 * t];
        float4 p4;
        p4.x = u * k4.x * v4.x;
        p4.y = u * k4.y * v4.y;
        p4.z = u * k4.z * v4.z;
        p4.w = u * k4.w * v4.w;
        ((float4*)(Pb + (size_t)i * N_))[t] = p4;
    }
}

extern "C" void kernel_launch(void* const* d_in, const int* in_sizes, int n_in,
                              void* d_out, int out_size, void* d_ws, size_t ws_size,
                              hipStream_t stream) {
    const float* M = (const float*)d_in[0];
    float* P = (float*)d_out;

    u64* ppk = (u64*)d_ws;                               // 2 MB
    u64* vpk = ppk + (size_t)B_ * G_ * N_;               // 64 KB
    // Stamps in [1,101] never collide with 0x00000000 or the harness's
    // 0xAAAAAAAA ws poison; memset is belt-and-braces for the first call.
    hipMemsetAsync(d_ws, 0,
                   ((size_t)B_ * G_ * N_ + (size_t)B_ * N_) * sizeof(u64),
                   stream);

    const size_t lds_bytes = (size_t)LDS_FLOATS * sizeof(float);
    (void)hipFuncSetAttribute((const void*)sinkhorn_kernel,
                              hipFuncAttributeMaxDynamicSharedMemorySize,
                              (int)lds_bytes);

    void* args[] = { (void*)&M, (void*)&P, (void*)&ppk, (void*)&vpk };
    hipError_t e = hipLaunchCooperativeKernel((void*)sinkhorn_kernel,
                                              dim3(B_ * G_), dim3(TPB),
                                              args, (unsigned)lds_bytes, stream);
    if (e != hipSuccess) {
        // fallback: 256 blocks at 1 block/CU on 256 CUs is co-resident,
        // which the packet dataflow requires
        sinkhorn_kernel<<<dim3(B_ * G_), dim3(TPB), lds_bytes, stream>>>(
            M, P, ppk, vpk);
    }
}

// Round 6
// 661.665 us; speedup vs baseline: 2.1360x; 2.1360x over previous
//
#include <hip/hip_runtime.h>
#include <math.h>

// Sinkhorn regularized transport, B=8, m=n=1024, fp32, 100 iterations.
//
// Round 6 = R4 protocol (best: 536us) + register-resident K.
//
// R5 lesson (1324us, WRITE 886MB): agent-scope packed-data polling streams
// at HBM; polls MUST hit a single dedicated flag line, bulk data read once.
// -> comm protocol reverted to R4 verbatim (stamp lines + single data read).
//
// R4 residual: 5.3us/iter = ~2.7 comm + ~2.2 LDS (K read twice + v) + ~0.6
// VALU. This round removes the LDS term: at 1 block/CU x 4 waves = 1
// wave/SIMD each wave owns the full 512-VGPR file, so K (512 B/thread) is
// held in registers in BOTH access layouts:
//   ka[32]   = K[i][4t..4t+3]            (phase A + epilogue layout)
//   kb[4][8] = K[4rq+ri][4cq+128jj ..+3] (phase B: 4-row reuse cuts v reads
//              4x; col mapping makes vl reads stride-16B conflict-free)
// Phases A/B are pure register FMA; per-iter LDS is ~36KB (u bcast + v).

#define B_    8
#define N_    1024
#define G_    32          // blocks per batch
#define RPB   32          // rows per block
#define KSTR  1028        // LDS staging row stride
#define NITER 100
#define TPB   256
#define LMB   10.0f
#define MAXD  5.0f

// LDS: Kl staging (reused only at init) + vl + ul + red
#define LDS_FLOATS (RPB * KSTR + N_ + RPB + 4 * G_)

typedef unsigned long long u64;

__device__ __forceinline__ void st8(float* p, float a, float b) {
    float2 f2 = make_float2(a, b);
    __hip_atomic_store((u64*)p, __builtin_bit_cast(u64, f2),
                       __ATOMIC_RELAXED, __HIP_MEMORY_SCOPE_AGENT);
}
__device__ __forceinline__ float2 ld8(const float* p) {
    u64 raw = __hip_atomic_load((const u64*)p,
                                __ATOMIC_RELAXED, __HIP_MEMORY_SCOPE_AGENT);
    return __builtin_bit_cast(float2, raw);
}
__device__ __forceinline__ void publish(int* s, int v) {
    __atomic_signal_fence(__ATOMIC_SEQ_CST);
    __hip_atomic_store(s, v, __ATOMIC_RELAXED, __HIP_MEMORY_SCOPE_AGENT);
}
// Wait until all 32 stamps reach tgt: one coalesced 128B line per poll.
__device__ __forceinline__ void poll32(const int* st, int tgt) {
    const int l = threadIdx.x & 31;
    for (;;) {
        int s = __hip_atomic_load(&st[l], __ATOMIC_RELAXED,
                                  __HIP_MEMORY_SCOPE_AGENT);
        if (__all(s >= tgt)) break;
        __builtin_amdgcn_s_sleep(2);
    }
    __atomic_signal_fence(__ATOMIC_SEQ_CST);
}

__global__ void __launch_bounds__(TPB, 1)
sinkhorn_kernel(const float* __restrict__ Mg,
                float* __restrict__ Pg,
                float* __restrict__ part,    // [2][B_][G_][N_]
                float* __restrict__ vbuf,    // [2][B_][N_]
                int* __restrict__ stA,       // [2][B_][G_]
                int* __restrict__ stV)       // [2][B_][G_]
{
    extern __shared__ float lds[];
    float* Kl   = lds;                        // staging only
    float* vl   = lds + RPB * KSTR;           // N_
    float* ul   = vl + N_;                    // RPB
    float4* red = (float4*)(ul + RPB);        // G_ float4

    const int b    = blockIdx.x & (B_ - 1);
    const int g    = blockIdx.x >> 3;
    const int t    = threadIdx.x;
    const int row0 = g * RPB;
    const int rq   = t >> 5;                  // 0..7  (4-row group)
    const int cq   = t & 31;                  // 0..31 (col lane)
    const float r = 1.0f / (float)N_;
    const float c = 1.0f / (float)N_;

    // ---- stage K rows into LDS (one-time) ----
    const float* Mb = Mg + ((size_t)b * N_ + row0) * N_;
    for (int i = 0; i < RPB; ++i) {
        float4 m4 = ((const float4*)(Mb + (size_t)i * N_))[t];
        float4 k4;
        k4.x = expf(-LMB * fminf(m4.x, MAXD));
        k4.y = expf(-LMB * fminf(m4.y, MAXD));
        k4.z = expf(-LMB * fminf(m4.z, MAXD));
        k4.w = expf(-LMB * fminf(m4.w, MAXD));
        *(float4*)&Kl[i * KSTR + 4 * t] = k4;
    }
    if (t < RPB) ul[t] = r;             // u = r initially
    __syncthreads();

    // ---- lift K into registers, both layouts (one-time) ----
    float4 ka[RPB];                     // K[i][4t..4t+3]
#pragma unroll
    for (int i = 0; i < RPB; ++i)
        ka[i] = *(const float4*)&Kl[i * KSTR + 4 * t];
    float4 kb[4][8];                    // K[4rq+ri][4cq+128jj ..+3]
#pragma unroll
    for (int ri = 0; ri < 4; ++ri)
#pragma unroll
        for (int jj = 0; jj < 8; ++jj)
            kb[ri][jj] = *(const float4*)&Kl[(4 * rq + ri) * KSTR
                                             + 4 * cq + 128 * jj];
    __syncthreads();                    // Kl dead from here on

    for (int it = 0; it <= NITER; ++it) {
        const int p   = it & 1;
        const int tgt = it + 1;
        int* stA_pb = stA + ((size_t)p * B_ + b) * G_;
        int* stV_pb = stV + ((size_t)p * B_ + b) * G_;

        // ---- phase A: partial[j] = sum_i K[i][j] * u_i (registers) ----
        float4 uu[8];
#pragma unroll
        for (int q = 0; q < 8; ++q)     // 8 broadcast b128 reads
            uu[q] = *(const float4*)&ul[4 * q];
        float4 a = make_float4(0.f, 0.f, 0.f, 0.f);
#pragma unroll
        for (int q = 0; q < 8; ++q) {
            const float us[4] = { uu[q].x, uu[q].y, uu[q].z, uu[q].w };
#pragma unroll
            for (int e = 0; e < 4; ++e) {
                const float4 k4 = ka[4 * q + e];
                const float u = us[e];
                a.x = fmaf(k4.x, u, a.x);
                a.y = fmaf(k4.y, u, a.y);
                a.z = fmaf(k4.z, u, a.z);
                a.w = fmaf(k4.w, u, a.w);
            }
        }
        float* slot = part + (((size_t)p * B_ + b) * G_ + g) * N_;
        st8(&slot[4 * t],     a.x, a.y);
        st8(&slot[4 * t + 2], a.z, a.w);

        __syncthreads();                     // drain all waves' stores to L3
        if (t == 0) publish(&stA_pb[g], tgt);

        // ---- owner-reduce: block g owns cols [32g, 32g+32) (R4 verbatim) --
        poll32(stA_pb, tgt);
        {
            const int gp = t >> 3;           // producer 0..31
            const int q  = t & 7;            // col quad within our slice
            const float* pb = part + (((size_t)p * B_ + b) * G_ + gp) * N_
                            + 32 * g + 4 * q;
            float2 s0 = ld8(pb);
            float2 s1 = ld8(pb + 2);
            float4 acc = make_float4(s0.x, s0.y, s1.x, s1.y);
#pragma unroll
            for (int d = 8; d <= 32; d <<= 1) {
                acc.x += __shfl_xor(acc.x, d);
                acc.y += __shfl_xor(acc.y, d);
                acc.z += __shfl_xor(acc.z, d);
                acc.w += __shfl_xor(acc.w, d);
            }
            if ((t & 63) < 8) red[(t >> 6) * 8 + (t & 63)] = acc;
        }
        __syncthreads();
        float* vb = vbuf + ((size_t)p * B_ + b) * N_;
        if (t < 8) {
            float4 y4;
            y4.x = red[t].x + red[8 + t].x + red[16 + t].x + red[24 + t].x;
            y4.y = red[t].y + red[8 + t].y + red[16 + t].y + red[24 + t].y;
            y4.z = red[t].z + red[8 + t].z + red[16 + t].z + red[24 + t].z;
            y4.w = red[t].w + red[8 + t].w + red[16 + t].w + red[24 + t].w;
            st8(&vb[32 * g + 4 * t],     c / y4.x, c / y4.y);
            st8(&vb[32 * g + 4 * t + 2], c / y4.z, c / y4.w);
        }
        if (t == 0) {
            __atomic_signal_fence(__ATOMIC_SEQ_CST);
            __builtin_amdgcn_s_waitcnt(0);   // wave-0's v stores at L3
            publish(&stV_pb[g], tgt);
        }

        // ---- broadcast: everyone reads full v (4KB) into LDS ----
        poll32(stV_pb, tgt);
        {
            float2 w0 = ld8(&vb[4 * t]);
            float2 w1 = ld8(&vb[4 * t + 2]);
            *(float4*)&vl[4 * t] = make_float4(w0.x, w0.y, w1.x, w1.y);
        }
        __syncthreads();

        if (it == NITER) break;              // vl holds final v

        // ---- phase B: z_i = sum_j K[i][j] v_j ; u_i = r / z_i (registers) -
        float z0 = 0.f, z1 = 0.f, z2 = 0.f, z3 = 0.f;
#pragma unroll
        for (int jj = 0; jj < 8; ++jj) {
            const float4 vv = *(const float4*)&vl[4 * cq + 128 * jj];
            z0 = fmaf(kb[0][jj].x, vv.x, z0); z0 = fmaf(kb[0][jj].y, vv.y, z0);
            z0 = fmaf(kb[0][jj].z, vv.z, z0); z0 = fmaf(kb[0][jj].w, vv.w, z0);
            z1 = fmaf(kb[1][jj].x, vv.x, z1); z1 = fmaf(kb[1][jj].y, vv.y, z1);
            z1 = fmaf(kb[1][jj].z, vv.z, z1); z1 = fmaf(kb[1][jj].w, vv.w, z1);
            z2 = fmaf(kb[2][jj].x, vv.x, z2); z2 = fmaf(kb[2][jj].y, vv.y, z2);
            z2 = fmaf(kb[2][jj].z, vv.z, z2); z2 = fmaf(kb[2][jj].w, vv.w, z2);
            z3 = fmaf(kb[3][jj].x, vv.x, z3); z3 = fmaf(kb[3][jj].y, vv.y, z3);
            z3 = fmaf(kb[3][jj].z, vv.z, z3); z3 = fmaf(kb[3][jj].w, vv.w, z3);
        }
#pragma unroll
        for (int d = 1; d <= 16; d <<= 1) {  // reduce over 32 cq lanes
            z0 += __shfl_xor(z0, d);
            z1 += __shfl_xor(z1, d);
            z2 += __shfl_xor(z2, d);
            z3 += __shfl_xor(z3, d);
        }
        if (cq == 0) {
            ul[4 * rq + 0] = r / z0;
            ul[4 * rq + 1] = r / z1;
            ul[4 * rq + 2] = r / z2;
            ul[4 * rq + 3] = r / z3;
        }
        __syncthreads();
    }

    // ---- epilogue: P[i][j] = u_i * K[i][j] * v_j (ka registers) ----
    float* Pb = Pg + ((size_t)b * N_ + row0) * N_;
    const float4 v4 = *(const float4*)&vl[4 * t];
    for (int i = 0; i < RPB; ++i) {
        const float u  = ul[i];
        const float4 k4 = ka[i];
        float4 p4;
        p4.x = u * k4.x * v4.x;
        p4.y = u * k4.y * v4.y;
        p4.z = u * k4.z * v4.z;
        p4.w = u * k4.w * v4.w;
        ((float4*)(Pb + (size_t)i * N_))[t] = p4;
    }
}

extern "C" void kernel_launch(void* const* d_in, const int* in_sizes, int n_in,
                              void* d_out, int out_size, void* d_ws, size_t ws_size,
                              hipStream_t stream) {
    const float* M = (const float*)d_in[0];
    float* P = (float*)d_out;

    const size_t part_floats = (size_t)2 * B_ * G_ * N_;   // 2 MB
    const size_t v_floats    = (size_t)2 * B_ * N_;        // 64 KB
    float* part = (float*)d_ws;
    float* vbuf = part + part_floats;
    int*   stA  = (int*)(vbuf + v_floats);
    int*   stV  = stA + 2 * B_ * G_;
    hipMemsetAsync(stA, 0, (size_t)4 * B_ * G_ * sizeof(int), stream);

    const size_t lds_bytes = (size_t)LDS_FLOATS * sizeof(float);
    (void)hipFuncSetAttribute((const void*)sinkhorn_kernel,
                              hipFuncAttributeMaxDynamicSharedMemorySize,
                              (int)lds_bytes);

    void* args[] = { (void*)&M, (void*)&P, (void*)&part, (void*)&vbuf,
                     (void*)&stA, (void*)&stV };
    hipError_t e = hipLaunchCooperativeKernel((void*)sinkhorn_kernel,
                                              dim3(B_ * G_), dim3(TPB),
                                              args, (unsigned)lds_bytes, stream);
    if (e != hipSuccess) {
        // fallback: 256 blocks at 1 block/CU on 256 CUs is co-resident,
        // which the stamp-flag dataflow requires
        sinkhorn_kernel<<<dim3(B_ * G_), dim3(TPB), lds_bytes, stream>>>(
            M, P, part, vbuf, stA, stV);
    }
}